// Round 6
// baseline (718.530 us; speedup 1.0000x reference)
//
#include <hip/hip_runtime.h>

// Problem constants (fixed by reference)
#define DIM 2048
#define NH 16
#define HD 128
#define NB 2
#define SEQ 4096
#define QKVC (3*DIM)            // 6144
#define EPS 1e-6f
#define LOG2E 1.4426950408889634f
#define SM_SCALE 0.08838834764831845f  // 1/sqrt(128)

typedef unsigned short u16;
typedef unsigned int u32;
typedef __attribute__((ext_vector_type(8))) short bf16x8;   // 8 bf16 = 4 VGPR (guide §3)
typedef __attribute__((ext_vector_type(4))) float f32x4;

#define GAS __attribute__((address_space(1)))
#define LAS __attribute__((address_space(3)))

// async global->LDS, 16B per lane, LDS dest = wave-uniform base + lane*16
__device__ __forceinline__ void gl_lds16(const void* g, void* l) {
  __builtin_amdgcn_global_load_lds((const GAS void*)g, (LAS void*)l, 16, 0, 0);
}

__device__ __forceinline__ u16 f2bf(float f) {   // RNE f32 -> bf16
  u32 u = __float_as_uint(f);
  u += 0x7fffu + ((u >> 16) & 1u);
  return (u16)(u >> 16);
}
__device__ __forceinline__ float bf2f(u32 h) { return __uint_as_float(h << 16); }

// pack two f32 -> two bf16 (round-half-up) in one u32: [hi16(e1) | hi16(e0)]
__device__ __forceinline__ u32 pack_bf2(float e0, float e1) {
  u32 a = __float_as_uint(e1) + 0x8000u;
  u32 b = __float_as_uint(e0) + 0x8000u;
  return __builtin_amdgcn_perm(a, b, 0x07060302u);
}

// ---------------- kernel 1: x fp32 -> bf16 ----------------
__global__ __launch_bounds__(256) void cast_x(const float* __restrict__ x,
                                              u16* __restrict__ xb) {
  int i = (blockIdx.x * 256 + threadIdx.x) * 4;
  float4 v = *(const float4*)(x + i);
  u16 o0 = f2bf(v.x), o1 = f2bf(v.y), o2 = f2bf(v.z), o3 = f2bf(v.w);
  *(ushort4*)(xb + i) = make_ushort4(o0, o1, o2, o3);
}

// ---------------- kernel 2: W (2048x6144) fp32 -> Wt (6144x2048) bf16 ----------------
__global__ __launch_bounds__(256) void cast_tw(const float* __restrict__ W,
                                               u16* __restrict__ Wt) {
  __shared__ u16 t[32][33];
  int n0 = blockIdx.x * 32, k0 = blockIdx.y * 32;
  int x = threadIdx.x & 31, y = threadIdx.x >> 5;      // y in 0..7
#pragma unroll
  for (int i = 0; i < 4; i++) {
    int r = y + 8 * i;
    t[r][x] = f2bf(W[(size_t)(k0 + r) * QKVC + n0 + x]);
  }
  __syncthreads();
#pragma unroll
  for (int i = 0; i < 4; i++) {
    int r = y + 8 * i;
    Wt[(size_t)(n0 + r) * DIM + k0 + x] = t[x][r];
  }
}

// ---------------- kernel 3: qkv = xb @ Wt^T + bias ----------------
// R6: 256x256-tile 8-phase schedule (guide §5 template, m201/m204). FROZEN since R6.
__global__ __launch_bounds__(512, 2) void gemm_qkv(const u16* __restrict__ A,   // 8192x2048
                                                   const u16* __restrict__ Bt,  // 6144x2048
                                                   const float* __restrict__ bias,
                                                   u16* __restrict__ C) {       // 8192x6144 bf16
  __shared__ __align__(16) u16 sm[65536];  // 128 KB: buf c at c*32768 (A 16384 + B 16384)
  // XCD-aware bijective swizzle (T1): nwg=768, 768%8==0
  const int lin = blockIdx.y * 24 + blockIdx.x;
  const int swz = (lin & 7) * 96 + (lin >> 3);
  const int nt = swz % 24, mt = swz / 24;
  const int tid = threadIdx.x, w = tid >> 6, l = tid & 63;
  const int lr = l & 15, quad = l >> 4;
  const int wq64 = (w >> 2) * 64;       // m sub-band inside each 128-row tile-half
  const int wn = (w & 3) * 64;          // n band
  const int srow = l >> 3;
  const int scs = ((l & 7) * 8) ^ ((srow & 4) << 2);   // pre-swizzled source col (elems)
  // swizzled ds_read lane base (elems): row*64 + kk*32 + (quad*8 ^ ((lr&4)<<2))
  const int qs = (quad * 8) ^ ((lr & 4) << 2);
  const int aBase = (wq64 + lr) * 64 + qs;
  const int bBase = (wn + lr) * 64 + qs + 16384;

  f32x4 acc[8][4] = {};
  bf16x8 af[4][2], b0[2][2], b1[2][2];

#define STAGE(t, kind, h)                                                        \
  do {                                                                           \
    const u16* _s = (kind) ? Bt : A;                                             \
    const int _rt = ((kind) ? nt : mt) * 256 + (h) * 128;                        \
    u16* _d = sm + ((t) & 1) * 32768 + (kind) * 16384 + (h) * 8192;              \
    _Pragma("unroll") for (int _j = 0; _j < 2; _j++) {                           \
      int _rl = w * 16 + _j * 8 + srow;                                          \
      gl_lds16(_s + (size_t)(_rt + _rl) * DIM + (t) * 64 + scs,                  \
               _d + (w * 16 + _j * 8) * 64);                                     \
    }                                                                            \
  } while (0)

#define LDA_H(c, mh)                                                             \
  _Pragma("unroll") for (int _mi = 0; _mi < 4; _mi++)                            \
  _Pragma("unroll") for (int _kk = 0; _kk < 2; _kk++)                            \
    af[_mi][_kk] = *(const bf16x8*)(sm + aBase + (c) * 32768 + (mh) * 8192 +     \
                                    _mi * 1024 + _kk * 32);

#define LDB_H(c, nh, dst)                                                        \
  _Pragma("unroll") for (int _ni = 0; _ni < 2; _ni++)                            \
  _Pragma("unroll") for (int _kk = 0; _kk < 2; _kk++)                            \
    dst[_ni][_kk] = *(const bf16x8*)(sm + bBase + (c) * 32768 + (nh) * 2048 +    \
                                     _ni * 1024 + _kk * 32);

#define MF(mh, nh, bsrc)                                                         \
  do {                                                                           \
    __builtin_amdgcn_s_setprio(1);                                               \
    _Pragma("unroll") for (int _mi = 0; _mi < 4; _mi++)                          \
    _Pragma("unroll") for (int _ni = 0; _ni < 2; _ni++)                          \
    _Pragma("unroll") for (int _kk = 0; _kk < 2; _kk++)                          \
      acc[(mh) * 4 + _mi][(nh) * 2 + _ni] =                                      \
          __builtin_amdgcn_mfma_f32_16x16x32_bf16(                               \
              af[_mi][_kk], bsrc[_ni][_kk],                                      \
              acc[(mh) * 4 + _mi][(nh) * 2 + _ni], 0, 0, 0);                     \
    __builtin_amdgcn_s_setprio(0);                                               \
  } while (0)

#define BAR() do { __builtin_amdgcn_sched_barrier(0); __builtin_amdgcn_s_barrier(); \
                   __builtin_amdgcn_sched_barrier(0); } while (0)
#define LGKM0() do { asm volatile("s_waitcnt lgkmcnt(0)" ::: "memory");          \
                     __builtin_amdgcn_sched_barrier(0); } while (0)
#define VMC(n) asm volatile("s_waitcnt vmcnt(" #n ")" ::: "memory")

  // prologue: tile0 -> buf0 (all 4 halves), tile1 -> buf1 (A-h0, B-h0, B-h1)
  STAGE(0, 0, 0); STAGE(0, 0, 1); STAGE(0, 1, 0); STAGE(0, 1, 1);
  STAGE(1, 0, 0); STAGE(1, 1, 0); STAGE(1, 1, 1);
  VMC(6);          // tile0 (8 oldest loads) landed; tile1's 3 halves stay in flight
  BAR();

#pragma unroll 1
  for (int i = 0; i < 16; i++) {      // 2 K-tiles per iteration (tiles 2i, 2i+1)
    const int t2 = 2 * i + 2, t3 = 2 * i + 3;
    const bool more = (i < 15);
    // ph1: tile 2i (buf0) quad (mh0,nh0); stage (2i+1).A-h1 -> buf1
    LDA_H(0, 0); LDB_H(0, 0, b0);
    STAGE(2 * i + 1, 0, 1);
    BAR(); LGKM0();
    MF(0, 0, b0);
    BAR();
    // ph2: quad (mh0,nh1); stage (2i+2).A-h0 -> buf0 (dead since ph1)
    LDB_H(0, 1, b1);
    if (more) STAGE(t2, 0, 0);
    BAR(); LGKM0();
    MF(0, 1, b1);
    BAR();
    // ph3: quad (mh1,nh1); stage (2i+2).B-h0 -> buf0 (dead since ph2)
    LDA_H(0, 1);
    if (more) STAGE(t2, 1, 0);
    BAR(); LGKM0();
    MF(1, 1, b1);
    BAR();
    // ph4: quad (mh1,nh0) from regs; stage (2i+2).B-h1; vmcnt -> tile 2i+1 complete
    if (more) { STAGE(t2, 1, 1); VMC(6); } else { VMC(0); }
    BAR();
    MF(1, 0, b0);
    BAR();
    // ph5: tile 2i+1 (buf1) quad (mh0,nh0); stage (2i+2).A-h1 -> buf0 (dead since ph3)
    LDA_H(1, 0); LDB_H(1, 0, b0);
    if (more) STAGE(t2, 0, 1);
    BAR(); LGKM0();
    MF(0, 0, b0);
    BAR();
    // ph6: quad (mh0,nh1); stage (2i+3).A-h0 -> buf1 (dead since ph5)
    LDB_H(1, 1, b1);
    if (more) STAGE(t3, 0, 0);
    BAR(); LGKM0();
    MF(0, 1, b1);
    BAR();
    // ph7: quad (mh1,nh1); stage (2i+3).B-h0 -> buf1 (dead since ph6)
    LDA_H(1, 1);
    if (more) STAGE(t3, 1, 0);
    BAR(); LGKM0();
    MF(1, 1, b1);
    BAR();
    // ph8: quad (mh1,nh0) from regs; stage (2i+3).B-h1; vmcnt -> tile 2i+2 complete
    if (more) { STAGE(t3, 1, 1); VMC(6); }
    BAR();
    MF(1, 0, b0);
    BAR();
  }
#undef STAGE
#undef LDA_H
#undef LDB_H
#undef MF
#undef BAR
#undef LGKM0
#undef VMC

  // epilogue: + bias, bf16 store. C/D layout: col=lane&15, row=quad*4+reg (m89/m91)
#pragma unroll
  for (int mh = 0; mh < 2; mh++)
#pragma unroll
    for (int mi = 0; mi < 4; mi++) {
      int rbase = mt * 256 + mh * 128 + wq64 + mi * 16 + quad * 4;
#pragma unroll
      for (int nh = 0; nh < 2; nh++)
#pragma unroll
        for (int ni = 0; ni < 2; ni++) {
          int col = nt * 256 + wn + nh * 32 + ni * 16 + lr;
          float bv = bias[col];
          f32x4 v = acc[mh * 4 + mi][nh * 2 + ni];
#pragma unroll
          for (int r = 0; r < 4; r++)
            C[(size_t)(rbase + r) * QKVC + col] = f2bf(v[r] + bv);
        }
    }
}

// ---------------- kernel 4: RMSNorm + RoPE + split, with FUSED V-transpose ----------------
// R9 fusion kept. Block = (64-token chunk c, head h); 4 waves; lane l owns dims 2l,2l+1.
// Q,K written as (b,h,n,d). V via padded LDS tile -> Vt (bh, d, n) directly.
// Q pre-scaled by SM_SCALE*LOG2E.
__global__ __launch_bounds__(256) void norm_rope(const u16* __restrict__ qkv,
                                                 const float* __restrict__ rot,
                                                 const float* __restrict__ qw,
                                                 const float* __restrict__ kw,
                                                 u16* __restrict__ Q, u16* __restrict__ K,
                                                 u16* __restrict__ Vt) {
  __shared__ u32 vt[64][68];   // [dpair][token] (pad 68: 272B row = 16B-aligned)
  const int c = blockIdx.x;    // token chunk: tokens c*64 .. c*64+63 (never straddles batch)
  const int h = blockIdx.y;
  const int w = threadIdx.x >> 6, l = threadIdx.x & 63;
  const float2 wq = *(const float2*)(qw + 2 * l);
  const float2 wk = *(const float2*)(kw + 2 * l);
  const int b = (c * 64) >> 12;
  const int bh = b * NH + h;
  const int n0 = (c * 64) & (SEQ - 1);

#pragma unroll 2
  for (int i = 0; i < 16; i++) {
    const int tl = w * 16 + i;
    const int tok = c * 64 + tl;
    const int n = tok & (SEQ - 1);
    const size_t base = (size_t)tok * QKVC + h * 384 + 6 * l;  // (d,j) layout, j innermost
    const u32* p = (const u32*)(qkv + base);
    u32 u0 = p[0], u1 = p[1], u2 = p[2];
    float q0 = bf2f(u0 & 0xffff), k0 = bf2f(u0 >> 16);
    float v0 = bf2f(u1 & 0xffff), q1 = bf2f(u1 >> 16);
    float k1 = bf2f(u2 & 0xffff), v1 = bf2f(u2 >> 16);
    float sq = q0 * q0 + q1 * q1, sk = k0 * k0 + k1 * k1;
#pragma unroll
    for (int m = 1; m < 64; m <<= 1) {
      sq += __shfl_xor(sq, m, 64);
      sk += __shfl_xor(sk, m, 64);
    }
    float rq = rsqrtf(sq * (1.0f / HD) + EPS) * (SM_SCALE * LOG2E);  // scale folded into Q
    float rk = rsqrtf(sk * (1.0f / HD) + EPS);
    float4 rr = *(const float4*)(rot + (size_t)(n * 64 + l) * 4);  // [cos,-sin,sin,cos]
    float qh0 = q0 * rq * wq.x, qh1 = q1 * rq * wq.y;
    float kh0 = k0 * rk * wk.x, kh1 = k1 * rk * wk.y;
    float qo0 = rr.x * qh0 + rr.y * qh1, qo1 = rr.z * qh0 + rr.w * qh1;
    float ko0 = rr.x * kh0 + rr.y * kh1, ko1 = rr.z * kh0 + rr.w * kh1;
    size_t o = ((size_t)bh * SEQ + n) * HD + 2 * l;
    *(u32*)(Q + o) = (u32)f2bf(qo0) | ((u32)f2bf(qo1) << 16);
    *(u32*)(K + o) = (u32)f2bf(ko0) | ((u32)f2bf(ko1) << 16);
    vt[l][tl] = (u32)f2bf(v0) | ((u32)f2bf(v1) << 16);   // d-pair (2l,2l+1) packed
  }
  __syncthreads();
  // write Vt[bh][d][n0..n0+63]: thread (d = tid>>1, half = tid&1) -> tokens 32h..32h+31
  const int d = threadIdx.x >> 1, half = threadIdx.x & 1;
  const int dp = d >> 1;
  const u32 sel = (d & 1) ? 0x07060302u : 0x05040100u;  // hi16s : lo16s of the pair words
  u32 ow[16];
#pragma unroll
  for (int j = 0; j < 16; j++) {
    u32 a = vt[dp][32 * half + 2 * j];       // token 32h+2j
    u32 bb = vt[dp][32 * half + 2 * j + 1];  // token 32h+2j+1
    ow[j] = __builtin_amdgcn_perm(bb, a, sel);  // [d@tok2j | d@tok2j+1<<16]
  }
  u16* dst = Vt + (size_t)bh * HD * SEQ + (size_t)d * SEQ + n0 + 32 * half;
#pragma unroll
  for (int j = 0; j < 4; j++)
    *((int4*)dst + j) = make_int4(ow[4 * j], ow[4 * j + 1], ow[4 * j + 2], ow[4 * j + 3]);
}

// ---------------- kernel 5: flash attention (S^T form, maxless softmax, mi=2) ----------------
// block = (qt, bh): 128 Q rows; wave w owns Q rows w*32..w*32+31 (2 x 16-row MFMA tiles).
// CLOSED THEORIES (do not revisit): R5 explicit dbuf (occupancy loss); R9 phase reorder
// (reg pressure); R10 XCD swizzle = FETCH 278->49 MB but time UNCHANGED (kernel is
// execution-mix bound: LDS ~55%, MFMA 34%, VALU/trans ~25% -- not traffic-bound).
// R11 (this round): T14 async-STAGE retry (m214 v27 isolated +17%), fixing R8's failure
// mode: NO arrays (8 named int4 + 8 precomputed per-lane pointers), loads issued BETWEEN
// g=0 and g=1 (short liveness: after g0's s[] die, before the g1 peak), ds_write at the
// loop top where the mandatory vmcnt(0) drain is free (loads had a half-tile to land).
// LDS stays 32 KB (single-buffer); ds_write addresses == gl_lds16 layout (verified R8,
// which PASSED correctness). Health check: WRITE_SIZE must stay 65.5 MB (no scratch).
// XCD swizzle kept (K/V L2-resident -> load latency ~200 cyc, easily hidden).
// S^T = mfma(kf, qf): lanes = qrows, (quad,reg) = keys. Key permutation in Ks staging
// makes exp(S^T) pack in-register into a K=32 B-operand for O^T = mfma(vf, pf).
// Maxless softmax: |score*scale*log2e| <= 16.3 -> fp32 exp2 safe.
// Q arrives pre-scaled by SM_SCALE*LOG2E (folded in norm_rope).
// XOR chunk swizzle (chunk ^= row&7) on Ks/Vs kills the 16-way bank conflicts.
__global__ __launch_bounds__(256, 2) void attn(const u16* __restrict__ Q,
                                               const u16* __restrict__ K,
                                               const u16* __restrict__ Vt,
                                               float* __restrict__ out) {
  __shared__ __align__(16) u16 smem[8192 + 8192];  // Ks 64x128 + Vs 128x64 = 32 KB
  u16* Ks = smem;
  u16* Vs = smem + 8192;
  // T1 XCD swizzle: 1024 blocks = 8 XCDs x 128. xcd = lin&7 -> contiguous 128-chunk.
  const int lin = blockIdx.y * 32 + blockIdx.x;
  const int nl = (lin & 7) * 128 + (lin >> 3);
  const int qt = nl & 31, bh = nl >> 5;
  const int tid = threadIdx.x, w = tid >> 6, l = tid & 63;
  const int lr = l & 15, quad = l >> 4;
  const size_t qb = (size_t)bh * SEQ * HD;
  const size_t vb = (size_t)bh * HD * SEQ;

  // Q fragments direct from global (B-operand: n=qrow on lanes, k=quad*8+j)
  bf16x8 qf[2][4];
#pragma unroll
  for (int mi = 0; mi < 2; mi++)
#pragma unroll
    for (int ks = 0; ks < 4; ks++)
      qf[mi][ks] = *(const bf16x8*)(Q + qb + (size_t)(qt * 128 + w * 32 + mi * 16 + lr) * HD +
                                    ks * 32 + quad * 8);

  // ---- T14 per-lane staging geometry (computed once; pointers, not arrays) ----
  // K: LDS row rl_i = w*16 + i*4 + quad; permuted key; col chunk (l&15)^(rl&7).
  // V: row_i = w*32 + i*8 + (l>>3); col chunk (l&7)^(row&7).
#define KGEOM(i, gp, lp)                                                         \
  {                                                                              \
    const int _rl = w * 16 + (i) * 4 + quad;                                     \
    const int _rem = _rl & 31;                                                   \
    const int _key = (_rl & 32) + ((_rem >> 2) & 3) * 8 + ((_rem >> 4) << 2) +   \
                     (_rem & 3);                                                 \
    gp = K + qb + (size_t)_key * HD + ((l & 15) ^ (_rl & 7)) * 8;                \
    lp = Ks + _rl * 128 + (l & 15) * 8;                                          \
  }
#define VGEOM(i, gp, lp)                                                         \
  {                                                                              \
    const int _row = w * 32 + (i) * 8 + (l >> 3);                                \
    gp = Vt + vb + (size_t)_row * SEQ + ((l & 7) ^ (_row & 7)) * 8;              \
    lp = Vs + _row * 64 + (l & 7) * 8;                                           \
  }
  const u16 *kp0, *kp1, *kp2, *kp3, *vp0, *vp1, *vp2, *vp3;
  u16 *lk0, *lk1, *lk2, *lk3, *lv0, *lv1, *lv2, *lv3;
  KGEOM(0, kp0, lk0) KGEOM(1, kp1, lk1) KGEOM(2, kp2, lk2) KGEOM(3, kp3, lk3)
  VGEOM(0, vp0, lv0) VGEOM(1, vp1, lv1) VGEOM(2, vp2, lv2) VGEOM(3, vp3, lv3)
#undef KGEOM
#undef VGEOM

  int4 k0r, k1r, k2r, k3r, v0r, v1r, v2r, v3r;   // staged tile (32 VGPR)
#define ISSUE(kt)                                                                \
  do {                                                                           \
    const size_t _ko = (size_t)(kt) * (64 * HD);                                 \
    const int _vo = (kt) * 64;                                                   \
    k0r = *(const int4*)(kp0 + _ko); k1r = *(const int4*)(kp1 + _ko);            \
    k2r = *(const int4*)(kp2 + _ko); k3r = *(const int4*)(kp3 + _ko);            \
    v0r = *(const int4*)(vp0 + _vo); v1r = *(const int4*)(vp1 + _vo);            \
    v2r = *(const int4*)(vp2 + _vo); v3r = *(const int4*)(vp3 + _vo);            \
  } while (0)

  f32x4 oacc[2][8] = {};
  float lacc[2] = {0.f, 0.f};

  ISSUE(0);   // prologue: tile 0 -> regs

  for (int kt = 0; kt < SEQ / 64; kt++) {
    __syncthreads();                               // all waves done reading tile kt-1
    asm volatile("s_waitcnt vmcnt(0)" ::: "memory");  // staged loads landed (free: issued >=half-tile ago)
    *(int4*)lk0 = k0r; *(int4*)lk1 = k1r; *(int4*)lk2 = k2r; *(int4*)lk3 = k3r;
    *(int4*)lv0 = v0r; *(int4*)lv1 = v1r; *(int4*)lv2 = v2r; *(int4*)lv3 = v3r;
    __syncthreads();                               // tile kt visible

#define GBLOCK(g)                                                                \
  {                                                                              \
    f32x4 s[2][2] = {};                                                          \
    _Pragma("unroll") for (int u = 0; u < 2; u++) {                              \
      bf16x8 kf[4];                                                              \
      _Pragma("unroll") for (int ks = 0; ks < 4; ks++) {                         \
        int row = (g) * 32 + u * 16 + lr;                                        \
        int ch = (ks * 4 + quad) ^ (row & 7);                                    \
        kf[ks] = *(const bf16x8*)(Ks + row * 128 + ch * 8);                      \
      }                                                                          \
      _Pragma("unroll") for (int ks = 0; ks < 4; ks++)                           \
      _Pragma("unroll") for (int mi = 0; mi < 2; mi++)                           \
        s[mi][u] = __builtin_amdgcn_mfma_f32_16x16x32_bf16(kf[ks], qf[mi][ks],   \
                                                           s[mi][u], 0, 0, 0);   \
    }                                                                            \
    bf16x8 pf[2];                                                                \
    _Pragma("unroll") for (int mi = 0; mi < 2; mi++) {                           \
      _Pragma("unroll") for (int u = 0; u < 2; u++)                              \
      _Pragma("unroll") for (int r = 0; r < 4; r++) {                            \
        float p = exp2f(s[mi][u][r]);                                            \
        s[mi][u][r] = p;                                                         \
        lacc[mi] += p;                                                           \
      }                                                                          \
      union { u32 w4[4]; bf16x8 v; } pk;                                         \
      _Pragma("unroll") for (int u = 0; u < 2; u++) {                            \
        pk.w4[u * 2 + 0] = pack_bf2(s[mi][u][0], s[mi][u][1]);                   \
        pk.w4[u * 2 + 1] = pack_bf2(s[mi][u][2], s[mi][u][3]);                   \
      }                                                                          \
      pf[mi] = pk.v;                                                             \
    }                                                                            \
    _Pragma("unroll") for (int di = 0; di < 8; di++) {                           \
      int row = di * 16 + lr;                                                    \
      int ch = (4 * (g) + quad) ^ (row & 7);                                     \
      bf16x8 vf = *(const bf16x8*)(Vs + row * 64 + ch * 8);                      \
      _Pragma("unroll") for (int mi = 0; mi < 2; mi++)                           \
        oacc[mi][di] = __builtin_amdgcn_mfma_f32_16x16x32_bf16(vf, pf[mi],       \
                                                               oacc[mi][di],     \
                                                               0, 0, 0);         \
    }                                                                            \
  }

    GBLOCK(0)
    // T14 issue point: g0's s[] dead, g1 compute (~1600 cyc) hides the L2 latency.
    if (kt + 1 < SEQ / 64) {
      ISSUE(kt + 1);
      __builtin_amdgcn_sched_barrier(0);   // pin issue here (don't sink past g1)
    }
    GBLOCK(1)
#undef GBLOCK
  }
#undef ISSUE

  // epilogue: reduce l across quads (2 shuffles, once), divide, coalesced float4 stores
  const int b = bh >> 4, h = bh & 15;
#pragma unroll
  for (int mi = 0; mi < 2; mi++) {
    float lsum = lacc[mi];
    lsum += __shfl_xor(lsum, 16, 64);
    lsum += __shfl_xor(lsum, 32, 64);
    float inv = 1.0f / lsum;
    int row = qt * 128 + w * 32 + mi * 16 + lr;
#pragma unroll
    for (int di = 0; di < 8; di++) {
      f32x4 o = oacc[mi][di];
      float4 v4 = make_float4(o[0] * inv, o[1] * inv, o[2] * inv, o[3] * inv);
      *(float4*)(out + ((size_t)(b * SEQ + row)) * DIM + h * HD + di * 16 + quad * 4) = v4;
    }
  }
}

// ---------------- launch ----------------
// ws layout (u16 elems; aliases are ordered by stream serialization):
//  [0        , 16777216)  xb   (later reused as Qb)
//  [16777216 , 29360128)  Wt
//  [29360128 , 79691776)  qkv
//  [79691776 , 96468992)  Kb
//  [96468992 ,113246208)  Vt   (written directly by norm_rope; read by attn)
// total 226,492,416 bytes required of ws_size.
extern "C" void kernel_launch(void* const* d_in, const int* in_sizes, int n_in,
                              void* d_out, int out_size, void* d_ws, size_t ws_size,
                              hipStream_t stream) {
  (void)in_sizes; (void)n_in; (void)out_size; (void)ws_size;
  const float* x    = (const float*)d_in[0];
  const float* rot  = (const float*)d_in[1];
  const float* W    = (const float*)d_in[2];
  const float* bias = (const float*)d_in[3];
  const float* qw   = (const float*)d_in[4];
  const float* kw   = (const float*)d_in[5];
  float* out = (float*)d_out;
  u16* ws  = (u16*)d_ws;
  u16* xb  = ws;
  u16* Wt  = ws + 16777216;
  u16* qkv = ws + 29360128;
  u16* Qb  = ws;               // alias xb (dead after gemm)
  u16* Kb  = ws + 79691776;
  u16* Vt  = ws + 96468992;

  hipLaunchKernelGGL(cast_x, dim3(16384), dim3(256), 0, stream, x, xb);
  hipLaunchKernelGGL(cast_tw, dim3(192, 64), dim3(256), 0, stream, W, Wt);
  hipLaunchKernelGGL(gemm_qkv, dim3(24, 32), dim3(512), 0, stream, xb, Wt, bias, qkv);
  hipLaunchKernelGGL(norm_rope, dim3(128, 16), dim3(256), 0, stream, qkv, rot, qw, kw, Qb, Kb, Vt);
  hipLaunchKernelGGL(attn, dim3(32, 32), dim3(256), 0, stream, Qb, Kb, Vt, out);
}